// Round 4
// baseline (2552.522 us; speedup 1.0000x reference)
//
#include <hip/hip_runtime.h>
#include <stdint.h>

typedef _Float16 f16;
typedef _Float16 h2 __attribute__((ext_vector_type(2)));
typedef float f4 __attribute__((ext_vector_type(4)));

union F4H { f4 v; h2 h[4]; f16 s[8]; };

__device__ __forceinline__ float fdot2(h2 a, h2 b, float c) {
    return __builtin_amdgcn_fdot2(a, b, c, false);
}

#define NB 64
#define NT 512
#define NH 256
#define NG 1024

// ---------------- workspace layout ----------------
// xc0 (layer-0 input transform) overlaps X1: xc0 is dead before k2 writes x1.
static const size_t OFF_H0   = 0;           // h0 f16  [64][512][256]   16,777,216 B
static const size_t OFF_X1   = 16777216;    // xc0/x1 f16 [64*512][1024] 67,108,864 B
static const size_t OFF_H1   = 83886080;    // h1 f16  [64][512][256]   16,777,216 B
static const size_t OFF_PL0  = 100663296;   // packed Whh0 [32][1024] f4  524,288 B
static const size_t OFF_PL1  = 101187584;   // packed Whh1                524,288 B
static const size_t OFF_WIH1 = 101711872;   // packed Wih1 [32][1024] f4  524,288 B
static const size_t OFF_B0C  = 102252544;   // bias0c f32 [1024]            4,096 B
static const size_t OFF_B1C  = 102256640;   // bias1c f32 [1024]            4,096 B
static const size_t OFF_WR1  = 102260736;   // wr1p f4 [32][128]           65,536 B
static const size_t OFF_MM   = 102326272;   // mmean f32 [64][256]         65,536 B
static const size_t OFF_M1S  = 102391808;   // m1sum f32 [64][128]         32,768 B
static const size_t OFF_HL   = 102424576;   // hh1last f32 [64][128]       32,768 B

// ---------------- packing kernels ----------------
// [1024][256] f32 row-major -> [32 k-groups][1024 cols] f4 (8 f16 each)
__global__ void pack_w256(const float* __restrict__ src, f4* __restrict__ dst)
{
    const int id = blockIdx.x * 256 + threadIdx.x;   // 32768 tasks
    const int j = id >> 5;
    const int g = id & 31;
    const float* s = src + j * 256 + g * 8;
    F4H u;
    #pragma unroll
    for (int i = 0; i < 8; ++i) u.s[i] = (f16)s[i];
    dst[g * 1024 + j] = u.v;
}

__global__ void pack_misc(const float* __restrict__ bih0, const float* __restrict__ bhh0,
                          const float* __restrict__ bih1, const float* __restrict__ bhh1,
                          const float* __restrict__ wr1,
                          float* __restrict__ bias0c, float* __restrict__ bias1c,
                          f4* __restrict__ wr1p)
{
    const int id = blockIdx.x * 256 + threadIdx.x;   // 6144 tasks
    if (id < 1024) {
        bias0c[id] = bih0[id] + bhh0[id];
    } else if (id < 2048) {
        const int j = id - 1024;
        bias1c[j] = bih1[j] + bhh1[j];
    } else {
        const int q = id - 2048;
        const int g = q >> 7, o = q & 127;
        F4H u;
        #pragma unroll
        for (int i = 0; i < 8; ++i)
            u.s[i] = (o < 100) ? (f16)wr1[o * 256 + g * 8 + i] : (f16)0.f;
        wr1p[g * 128 + o] = u.v;
    }
}

// ---------------- K0: xc0 = x @ Wih0^T + bias0 (f32 math, f16 store) ----------------
// x [64*512][8] f32, Wih0 [1024][8] f32 -> xc [64*512][1024] f16
__global__ __launch_bounds__(256)
void k0_xc(const float* __restrict__ x, const float* __restrict__ wih0,
           const float* __restrict__ b0c, f16* __restrict__ xc)
{
    __shared__ float xs[512];                 // 64 rows x 8
    const int l = threadIdx.x;
    const int r0 = blockIdx.x * 64;
    xs[l]       = x[r0 * 8 + l];
    xs[l + 256] = x[r0 * 8 + l + 256];
    __syncthreads();

    #pragma unroll 1
    for (int pass = 0; pass < 4; ++pass) {
        const int col = pass * 256 + l;
        const f4* wp = (const f4*)(wih0 + col * 8);
        f4 w0 = wp[0], w1 = wp[1];
        float bb = b0c[col];
        #pragma unroll 4
        for (int r = 0; r < 64; ++r) {
            const float* xr = xs + r * 8;
            float acc = bb;
            acc += xr[0] * w0[0] + xr[1] * w0[1] + xr[2] * w0[2] + xr[3] * w0[3];
            acc += xr[4] * w1[0] + xr[5] * w1[1] + xr[6] * w1[2] + xr[7] * w1[3];
            xc[(size_t)(r0 + r) * NG + col] = (f16)acc;
        }
    }
}

// ---------------- LSTM chain kernel ----------------
// 512 threads, one WG per batch element; thread t owns gate cols t and t+512
// (round-1 proven mapping). k-split (32 groups of 8):
//   groups [0,3)  : LDS (48 KB)
//   groups [3,8)  : registers (wrA/wrB, 40 VGPR)
//   groups [8,32) : streamed from L2, 8 phases x 3 groups, double-buffered.
// LDS total ~56.5 KB (gates deliberately padded to 8 KB): keeps the backend's
// LDS-occupancy heuristic at 2 WGs/CU -> 4 waves/SIMD -> 128-VGPR budget,
// which this kernel fits WITHOUT spilling (peak live ~115).
#define DOT8(wa_, wb_, hh_) { F4H wa_u; wa_u.v = (wa_); F4H wb_u; wb_u.v = (wb_); F4H hh_u; hh_u.v = (hh_); \
    a0  = fdot2(wa_u.h[0], hh_u.h[0], a0 ); a1  = fdot2(wb_u.h[0], hh_u.h[0], a1 ); \
    a0b = fdot2(wa_u.h[1], hh_u.h[1], a0b); a1b = fdot2(wb_u.h[1], hh_u.h[1], a1b); \
    a0  = fdot2(wa_u.h[2], hh_u.h[2], a0 ); a1  = fdot2(wb_u.h[2], hh_u.h[2], a1 ); \
    a0b = fdot2(wa_u.h[3], hh_u.h[3], a0b); a1b = fdot2(wb_u.h[3], hh_u.h[3], a1b); }

template<int LAYER>
__global__ __launch_bounds__(512)
void lstm_chain(const f16* __restrict__ xc,       // [b][t][1024] f16, bias folded
                const f4* __restrict__ pack,      // [32][1024] f4
                f16* __restrict__ hout,
                float* __restrict__ mmean)
{
    __shared__ f4 wlds[3 * 1024];                 // 48 KB
    __shared__ float gates[2048];                 // 8 KB (padded occupancy knob)
    __shared__ __align__(16) f16 hsh[256];        // 512 B

    const int t = threadIdx.x;
    const int b = blockIdx.x;
    const int j0 = t, j1 = t + 512;

    #pragma unroll
    for (int i = 0; i < 6; ++i) wlds[t + 512 * i] = pack[t + 512 * i];

    f4 wrA[5], wrB[5];
    #pragma unroll
    for (int g = 0; g < 5; ++g) {
        wrA[g] = pack[(3 + g) * 1024 + j0];
        wrB[g] = pack[(3 + g) * 1024 + j1];
    }

    if (t < 32) { f4 zz = {0.f, 0.f, 0.f, 0.f}; ((f4*)hsh)[t] = zz; }

    float cst = 0.f, hsum = 0.f;
    __syncthreads();

    const f4* str = pack + 8 * 1024;              // streamed groups 8..31
    f16* houtb = hout + (size_t)b * NT * NH;
    const f16* xb = xc + (size_t)b * NT * NG;

    #pragma unroll 1
    for (int tt = 0; tt < NT; ++tt) {
        f4 pA0[3], pA1[3], pB0[3], pB1[3];
        // issue phase 0 (groups 8..10)
        #pragma unroll
        for (int g = 0; g < 3; ++g) { pA0[g] = str[g * 1024 + j0]; pA1[g] = str[g * 1024 + j1]; }
        // x contribution (precomputed, bias folded)
        const f16* xr = xb + (size_t)tt * NG;
        float a0 = (float)xr[j0];
        float a1 = (float)xr[j1];
        float a0b = 0.f, a1b = 0.f;
        // issue phase 1 (groups 11..13)
        #pragma unroll
        for (int g = 0; g < 3; ++g) { pB0[g] = str[(3 + g) * 1024 + j0]; pB1[g] = str[(3 + g) * 1024 + j1]; }

        const f4* hv4 = (const f4*)hsh;

        // LDS groups 0..2
        #pragma unroll
        for (int i = 0; i < 3; ++i) DOT8(wlds[i * 1024 + j0], wlds[i * 1024 + j1], hv4[i]);

        // 8 streamed phases of 3 groups; reg-group filler between phases
        #pragma unroll
        for (int p = 0; p < 8; ++p) {
            if ((p & 1) == 0) {
                #pragma unroll
                for (int g = 0; g < 3; ++g) DOT8(pA0[g], pA1[g], hv4[8 + 3 * p + g]);
                if (p < 6) {
                    #pragma unroll
                    for (int g = 0; g < 3; ++g) {
                        pA0[g] = str[((p + 2) * 3 + g) * 1024 + j0];
                        pA1[g] = str[((p + 2) * 3 + g) * 1024 + j1];
                    }
                }
            } else {
                #pragma unroll
                for (int g = 0; g < 3; ++g) DOT8(pB0[g], pB1[g], hv4[8 + 3 * p + g]);
                if (p < 6) {
                    #pragma unroll
                    for (int g = 0; g < 3; ++g) {
                        pB0[g] = str[((p + 2) * 3 + g) * 1024 + j0];
                        pB1[g] = str[((p + 2) * 3 + g) * 1024 + j1];
                    }
                }
            }
            if (p < 5) DOT8(wrA[p], wrB[p], hv4[3 + p]);
        }

        gates[j0] = a0 + a0b;
        gates[j1] = a1 + a1b;
        __syncthreads();

        if (t < 256) {
            float gi = gates[t];
            float gf = gates[t + 256];
            float gg = gates[t + 512];
            float go = gates[t + 768];
            float si = 1.f / (1.f + __expf(-gi));
            float sf = 1.f / (1.f + __expf(-gf));
            float so = 1.f / (1.f + __expf(-go));
            float tg = 1.f - 2.f / (__expf(2.f * gg) + 1.f);   // tanh, NaN-safe
            cst = sf * cst + si * tg;
            float th = 1.f - 2.f / (__expf(2.f * cst) + 1.f);
            float hvl = so * th;
            hsh[t] = (f16)hvl;
            if (LAYER == 1) hsum += hvl;
        }
        __syncthreads();

        if (t < 32) ((f4*)(houtb + (size_t)tt * NH))[t] = ((const f4*)hsh)[t];
    }
    if (LAYER == 1 && t < 256) mmean[b * NH + t] = hsum * (1.f / 512.f);
}

// ---------------- K2: x1 = h0 @ Wih1^T + bias1 (proven) ----------------
__global__ __launch_bounds__(256)
void k2_gemm(const f16* __restrict__ h0, const f4* __restrict__ wih1p,
             const float* __restrict__ b1c, f16* __restrict__ x1)
{
    __shared__ __align__(16) f16 ash[64 * 256];   // 32 KB A-tile (64 rows x 256 k)
    const int l = threadIdx.x;
    const size_t m0 = (size_t)blockIdx.x * 64;
    const f4* src = (const f4*)(h0 + m0 * 256);
    f4* dst = (f4*)ash;
    #pragma unroll
    for (int i = 0; i < 8; ++i) dst[l + 256 * i] = src[l + 256 * i];
    __syncthreads();

    const int lane = l & 63;
    const int rg4 = l >> 6;
    #pragma unroll 1
    for (int pass = 0; pass < 16; ++pass) {
        const int rgrp = pass >> 2;
        const int nc = pass & 3;
        const int row0 = rgrp * 16 + rg4 * 4;
        const int col0 = nc * 256 + lane;
        float acc[4][4];
        float bq[4];
        #pragma unroll
        for (int q = 0; q < 4; ++q) bq[q] = b1c[col0 + 64 * q];
        #pragma unroll
        for (int r = 0; r < 4; ++r)
            #pragma unroll
            for (int q = 0; q < 4; ++q) acc[r][q] = bq[q];

        for (int u = 0; u < 32; ++u) {
            f4 wv[4];
            #pragma unroll
            for (int q = 0; q < 4; ++q) wv[q] = wih1p[u * 1024 + col0 + 64 * q];
            #pragma unroll
            for (int r = 0; r < 4; ++r) {
                F4H av; av.v = ((const f4*)ash)[(row0 + r) * 32 + u];
                #pragma unroll
                for (int q = 0; q < 4; ++q) {
                    F4H wq; wq.v = wv[q];
                    #pragma unroll
                    for (int p = 0; p < 4; ++p) acc[r][q] = fdot2(av.h[p], wq.h[p], acc[r][q]);
                }
            }
        }
        #pragma unroll
        for (int r = 0; r < 4; ++r)
            #pragma unroll
            for (int q = 0; q < 4; ++q)
                x1[(m0 + row0 + r) * 1024 + col0 + 64 * q] = (f16)acc[r][q];
    }
}

// ---------------- K4a (proven) ----------------
__global__ __launch_bounds__(256)
void k4a(const f16* __restrict__ h1, const float* __restrict__ mmean,
         const float* __restrict__ Wl1, const float* __restrict__ b1,
         const f4* __restrict__ wr1p, float* __restrict__ m1sum,
         float* __restrict__ hh1last)
{
    __shared__ __align__(16) f16 ash[64 * 256];   // 32 KB h1 chunk
    __shared__ float msh[256];
    __shared__ float mbase[128];
    __shared__ float red[256];
    const int l = threadIdx.x;
    const int b = blockIdx.x >> 3;
    const int ch = blockIdx.x & 7;

    const f4* src = (const f4*)(h1 + ((size_t)b * 512 + ch * 64) * 256);
    f4* dst = (f4*)ash;
    #pragma unroll
    for (int i = 0; i < 8; ++i) dst[l + 256 * i] = src[l + 256 * i];
    msh[l] = mmean[b * 256 + l];
    __syncthreads();

    if (l < 128) {
        float acc = 0.f;
        if (l < 100) {
            acc = b1[l];
            const float* wrow = Wl1 + l * 256;
            for (int j = 0; j < 256; ++j) acc += msh[j] * wrow[j];
        }
        mbase[l] = acc;
    }
    __syncthreads();

    const int o = l & 127;
    const int th = l >> 7;
    float sumloc = 0.f;
    float last = 0.f;
    #pragma unroll 1
    for (int it = 0; it < 32; ++it) {
        const int tloc = it * 2 + th;
        float acc = mbase[o];
        const f4* arow = (const f4*)(ash + tloc * 256);
        #pragma unroll
        for (int u = 0; u < 32; ++u) {
            F4H av; av.v = arow[u];
            F4H wv; wv.v = wr1p[u * 128 + o];
            #pragma unroll
            for (int p = 0; p < 4; ++p) acc = fdot2(av.h[p], wv.h[p], acc);
        }
        float e = acc > 0.f ? acc : (__expf(acc) - 1.f);
        sumloc += e;
        if (tloc == 63) last = e;
    }
    red[l] = sumloc;
    __syncthreads();
    if (l < 128) {
        float s = red[l] + red[l + 128];
        if (l < 100) atomicAdd(m1sum + b * 128 + l, s);
    }
    if (ch == 7 && th == 1) hh1last[b * 128 + o] = last;
}

// ---------------- K4b: final head (proven) ----------------
__global__ __launch_bounds__(128)
void k4b(const float* __restrict__ m1sum, const float* __restrict__ hh1last,
         const float* __restrict__ Wl2, const float* __restrict__ Wr2,
         const float* __restrict__ b2,
         const float* __restrict__ Wfc1, const float* __restrict__ bfc1,
         const float* __restrict__ Wfc2, const float* __restrict__ bfc2,
         float* __restrict__ out)
{
    __shared__ float m1s[128];
    __shared__ float hl[128];
    __shared__ float s[128];
    __shared__ float zsh[512];
    const int b = blockIdx.x;
    const int l = threadIdx.x;

    m1s[l] = m1sum[b * 128 + l] * (1.f / 512.f);
    hl[l] = hh1last[b * 128 + l];
    __syncthreads();

    {
        float acc = b2[l];
        const float* wl2r = Wl2 + l * 100;
        const float* wr2r = Wr2 + l * 100;
        for (int j = 0; j < 100; ++j) acc += m1s[j] * wl2r[j] + hl[j] * wr2r[j];
        s[l] = acc;
    }
    __syncthreads();

    #pragma unroll 1
    for (int i = 0; i < 4; ++i) {
        const int idx = l + 128 * i;
        const int k = idx >> 6, o = idx & 63;
        const float* w = Wfc1 + (size_t)(k * 64 + o) * 128;
        float a = bfc1[k * 64 + o];
        for (int d = 0; d < 128; ++d) a += s[d] * w[d];
        zsh[idx] = a > 0.f ? a : 0.f;
    }
    __syncthreads();

    #pragma unroll 1
    for (int i = 0; i < 2; ++i) {
        const int idx = l + 128 * i;
        if (idx < 192) {
            const int k = idx / 24, p = idx % 24;
            const float* w = Wfc2 + (size_t)(k * 24 + p) * 64;
            float a = bfc2[k * 24 + p];
            const float* z = zsh + k * 64;
            for (int d = 0; d < 64; ++d) a += z[d] * w[d];
            out[(size_t)(k * 64 + b) * 24 + p] = a;
        }
    }
}

// ---------------- launch ----------------
extern "C" void kernel_launch(void* const* d_in, const int* in_sizes, int n_in,
                              void* d_out, int out_size, void* d_ws, size_t ws_size,
                              hipStream_t stream)
{
    const float* x    = (const float*)d_in[0];
    const float* Wih0 = (const float*)d_in[1];
    const float* Whh0 = (const float*)d_in[2];
    const float* bih0 = (const float*)d_in[3];
    const float* bhh0 = (const float*)d_in[4];
    const float* Wih1 = (const float*)d_in[5];
    const float* Whh1 = (const float*)d_in[6];
    const float* bih1 = (const float*)d_in[7];
    const float* bhh1 = (const float*)d_in[8];
    const float* Wl1  = (const float*)d_in[9];
    const float* Wr1  = (const float*)d_in[10];
    const float* b1   = (const float*)d_in[11];
    const float* Wl2  = (const float*)d_in[12];
    const float* Wr2  = (const float*)d_in[13];
    const float* b2   = (const float*)d_in[14];
    const float* Wfc1 = (const float*)d_in[15];
    const float* bfc1 = (const float*)d_in[16];
    const float* Wfc2 = (const float*)d_in[17];
    const float* bfc2 = (const float*)d_in[18];

    char* ws = (char*)d_ws;
    f16*   h0f   = (f16*)(ws + OFF_H0);
    f16*   x1f   = (f16*)(ws + OFF_X1);    // xc0 shares this slot (dead before k2)
    f16*   h1f   = (f16*)(ws + OFF_H1);
    f4*    pl0   = (f4*)(ws + OFF_PL0);
    f4*    pl1   = (f4*)(ws + OFF_PL1);
    f4*    wih1p = (f4*)(ws + OFF_WIH1);
    float* b0c   = (float*)(ws + OFF_B0C);
    float* b1c   = (float*)(ws + OFF_B1C);
    f4*    wr1p  = (f4*)(ws + OFF_WR1);
    float* mm    = (float*)(ws + OFF_MM);
    float* m1s   = (float*)(ws + OFF_M1S);
    float* hhl   = (float*)(ws + OFF_HL);

    pack_w256<<<128, 256, 0, stream>>>(Whh0, pl0);
    pack_w256<<<128, 256, 0, stream>>>(Whh1, pl1);
    pack_w256<<<128, 256, 0, stream>>>(Wih1, wih1p);
    pack_misc<<<24, 256, 0, stream>>>(bih0, bhh0, bih1, bhh1, Wr1, b0c, b1c, wr1p);
    hipMemsetAsync(m1s, 0, 64 * 128 * sizeof(float), stream);

    // xc0 = x @ Wih0^T + b0  (into the X1 slot)
    k0_xc<<<512, 256, 0, stream>>>(x, Wih0, b0c, x1f);
    // layer-0 chain
    lstm_chain<0><<<64, 512, 0, stream>>>(x1f, pl0, h0f, (float*)nullptr);
    // x1 = h0 @ Wih1^T + b1  (overwrites xc0 slot, xc0 dead)
    k2_gemm<<<512, 256, 0, stream>>>(h0f, wih1p, b1c, x1f);
    // layer-1 chain (+ mean over t)
    lstm_chain<1><<<64, 512, 0, stream>>>(x1f, pl1, h1f, mm);
    // head
    k4a<<<512, 256, 0, stream>>>(h1f, mm, Wl1, b1, wr1p, m1s, hhl);
    k4b<<<64, 128, 0, stream>>>(m1s, hhl, Wl2, Wr2, b2, Wfc1, bfc1, Wfc2, bfc2, (float*)d_out);
}